// Round 13
// baseline (195.537 us; speedup 1.0000x reference)
//
#include <hip/hip_runtime.h>

// ClassicalSelfAttention: B=1, N=4096, D=768, H=12, Hd=64, fp32 in/out.
// R22 = R17 reverted exactly (R21's falsifier fired: S=2 + BK=128 netted +3.8us;
// attn S=2 66.1 > S=4 64.8, occupancy 25%<31%), PLUS a measurement change:
// attn launched as TWO back-to-back 768-block dispatches (sp_base 0 / 2, nsl8=3
// per half). Each half = 3 blocks/CU uniform fill at bound-4, ~33us -> (a) any
// kernel >=33us (gemm_qkv?) surfaces in top-5 with its true duration; (b) the
// Start(h2)-End(h1) timestamp delta directly measures the graph inter-dispatch
// gap. Pre-committed: gap>8us -> fuse combine into gemm_out next; gap<4us ->
// attack largest revealed kernel.
// Config: S=4, gemm_qkv 128x96 grid(24,32), gemm_out 64^2 BK=64 grid(12,64),
// attn 128 q-rows/block DMA-staged LDS bound-4. All verified at 189.3us (R17).

typedef __attribute__((ext_vector_type(8))) short short8;   // 8 x bf16 fragment
typedef __attribute__((ext_vector_type(4))) float f32x4;    // MFMA accumulator

#define N_TOK 4096
#define NHEAD 12
#define DMODEL 768
#define QK_LD 1536

#if defined(__has_builtin)
#if __has_builtin(__builtin_amdgcn_exp2f)
#define EXP2F __builtin_amdgcn_exp2f
#else
#define EXP2F exp2f
#endif
#else
#define EXP2F exp2f
#endif

#if defined(__has_builtin)
#if __has_builtin(__builtin_amdgcn_perm)
#define PACK2BF(hi, lo) __builtin_amdgcn_perm((hi), (lo), 0x07060302u)
#else
#define PACK2BF(hi, lo) ((((hi)) & 0xffff0000u) | (((lo)) >> 16))
#endif
#else
#define PACK2BF(hi, lo) ((((hi)) & 0xffff0000u) | (((lo)) >> 16))
#endif

__device__ __forceinline__ ushort bf16bits(float x) {
  union { float f; unsigned u; } cv; cv.f = x;
  unsigned u = cv.u;
  u += 0x7fffu + ((u >> 16) & 1u);   // RNE
  return (ushort)(u >> 16);
}
__device__ __forceinline__ float bf2f(ushort u) {
  return __uint_as_float(((unsigned)u) << 16);
}

// async global->LDS, 16 B per lane; lds base must be wave-uniform, HW scatters lane*16.
__device__ __forceinline__ void async16(ushort* lds, const ushort* g) {
  __builtin_amdgcn_global_load_lds((const __attribute__((address_space(1))) unsigned int*)g,
                                   (__attribute__((address_space(3))) unsigned int*)lds,
                                   16, 0, 0);
}

// ---- fused fp32->bf16 converts for x (3072 blk), w_qkv (1728 blk), w_out (576 blk) ----
__global__ void __launch_bounds__(256) cvt3(const float* __restrict__ x,
                                            const float* __restrict__ wq,
                                            const float* __restrict__ wo,
                                            ushort* __restrict__ xb,
                                            ushort* __restrict__ wqb,
                                            ushort* __restrict__ wob) {
  const int b = blockIdx.x, t = threadIdx.x;
  const float* src; ushort* dst; int i;
  if (b < 3072)      { src = x;  dst = xb;  i = b * 256 + t; }           // 786432 f4
  else if (b < 4800) { src = wq; dst = wqb; i = (b - 3072) * 256 + t; }  // 442368 f4
  else               { src = wo; dst = wob; i = (b - 4800) * 256 + t; }  // 147456 f4
  const float4 v = ((const float4*)src)[i];
  ushort4 o;
  o.x = bf16bits(v.x); o.y = bf16bits(v.y); o.z = bf16bits(v.z); o.w = bf16bits(v.w);
  ((ushort4*)dst)[i] = o;
}

#define GEMM_STAGE(Ms, Mp, MK)                                                 \
  do {                                                                         \
    _Pragma("unroll")                                                          \
    for (int i_ = 0; i_ < 4; i_++)                                             \
      async16(&Ms[(wave * 32 + i_ * 8) * 64],                                  \
              Mp + (size_t)(wave * 32 + i_ * 8 + lrow) * (MK) + lcol);         \
  } while (0)

#define GEMM_STAGE96(Ms, Mp, MK)                                               \
  do {                                                                         \
    _Pragma("unroll")                                                          \
    for (int i_ = 0; i_ < 3; i_++)                                             \
      async16(&Ms[(wave * 24 + i_ * 8) * 64],                                  \
              Mp + (size_t)(wave * 24 + i_ * 8 + lrow) * (MK) + lcol);         \
  } while (0)

#define GEMM_STAGE64(Ms, Mp, MK)                                               \
  do {                                                                         \
    _Pragma("unroll")                                                          \
    for (int i_ = 0; i_ < 2; i_++)                                             \
      async16(&Ms[(wave * 16 + i_ * 8) * 64],                                  \
              Mp + (size_t)(wave * 16 + i_ * 8 + lrow) * (MK) + lcol);         \
  } while (0)

// ---- GEMM1: qkv = x @ w_qkv^T.  128x96 tiles, grid 24x32 = 768 = 3/CU exact.
__global__ void __launch_bounds__(256) gemm_qkv(const ushort* __restrict__ A,
                                                const ushort* __restrict__ B,
                                                ushort* __restrict__ qkb,
                                                ushort* __restrict__ vtg) {
  __shared__ __align__(16) ushort As[128 * 64];
  __shared__ __align__(16) ushort Bs[96 * 64];
  const int tid = threadIdx.x;
  const int wave = tid >> 6, lane = tid & 63, quad = lane >> 4, l16 = lane & 15;
  const int wm = wave & 1, wn = wave >> 1;
  const int lrow = lane >> 3, lcol = (lane & 7) * 8;
  const int m0 = blockIdx.y * 128, n0 = blockIdx.x * 96;
  const int K = DMODEL;

  f32x4 acc[4][3] = {};
  const ushort* Ap = A + (size_t)m0 * K;
  const ushort* Bp = B + (size_t)n0 * K;

  for (int k0 = 0; k0 < K; k0 += 64) {
    GEMM_STAGE(As, Ap + k0, K);
    GEMM_STAGE96(Bs, Bp + k0, K);
    __syncthreads();   // drains vmcnt -> staged data visible
#pragma unroll
    for (int ks = 0; ks < 2; ks++) {
      short8 af[4], bf[3];
#pragma unroll
      for (int i = 0; i < 4; i++)
        af[i] = *(const short8*)&As[(wm * 64 + i * 16 + l16) * 64 + ks * 32 + quad * 8];
#pragma unroll
      for (int i = 0; i < 3; i++)
        bf[i] = *(const short8*)&Bs[(wn * 48 + i * 16 + l16) * 64 + ks * 32 + quad * 8];
#pragma unroll
      for (int mi = 0; mi < 4; mi++)
#pragma unroll
        for (int ni = 0; ni < 3; ni++)
          acc[mi][ni] = __builtin_amdgcn_mfma_f32_16x16x32_bf16(af[mi], bf[ni], acc[mi][ni], 0, 0, 0);
    }
    __syncthreads();
  }

  if (n0 < QK_LD) {
    const float qsc = (n0 < 768) ? 0.18033688011112042f : 1.0f;  // log2(e)/8
#pragma unroll
    for (int mi = 0; mi < 4; mi++)
#pragma unroll
      for (int ni = 0; ni < 3; ni++) {
        const int col = n0 + wn * 48 + ni * 16 + l16;
#pragma unroll
        for (int rr = 0; rr < 4; rr++) {
          const int row = m0 + wm * 64 + mi * 16 + quad * 4 + rr;
          qkb[(size_t)row * QK_LD + col] = bf16bits(acc[mi][ni][rr] * qsc);
        }
      }
  } else {
#pragma unroll
    for (int mi = 0; mi < 4; mi++)
#pragma unroll
      for (int ni = 0; ni < 3; ni++) {
        const int col = n0 + wn * 48 + ni * 16 + l16 - QK_LD;   // = h*64+d
        const int rowb = m0 + wm * 64 + mi * 16 + quad * 4;
        const unsigned u0 = (unsigned)bf16bits(acc[mi][ni][0]) |
                            ((unsigned)bf16bits(acc[mi][ni][1]) << 16);
        const unsigned u1 = (unsigned)bf16bits(acc[mi][ni][2]) |
                            ((unsigned)bf16bits(acc[mi][ni][3]) << 16);
        *(uint2*)&vtg[(size_t)col * N_TOK + rowb] = make_uint2(u0, u1);
      }
  }
}

// ---- GEMM2: out = aout @ w_out^T + bias (fp32 out), 64x64 tiles, 768 = 3/CU ----
__global__ void __launch_bounds__(256) gemm_out(const ushort* __restrict__ A,
                                                const ushort* __restrict__ B,
                                                float* __restrict__ Cf,
                                                const float* __restrict__ bias) {
  __shared__ __align__(16) ushort As[64 * 64];
  __shared__ __align__(16) ushort Bs[64 * 64];
  const int tid = threadIdx.x;
  const int wave = tid >> 6, lane = tid & 63, quad = lane >> 4, l16 = lane & 15;
  const int wm = wave & 1, wn = wave >> 1;
  const int lrow = lane >> 3, lcol = (lane & 7) * 8;
  const int m0 = blockIdx.y * 64, n0 = blockIdx.x * 64;
  const int K = DMODEL, Nn = DMODEL;

  f32x4 acc[2][2] = {};
  const ushort* Ap = A + (size_t)m0 * K;
  const ushort* Bp = B + (size_t)n0 * K;

  for (int k0 = 0; k0 < K; k0 += 64) {
    GEMM_STAGE64(As, Ap + k0, K);
    GEMM_STAGE64(Bs, Bp + k0, K);
    __syncthreads();
#pragma unroll
    for (int ks = 0; ks < 2; ks++) {
      short8 af[2], bf[2];
#pragma unroll
      for (int i = 0; i < 2; i++) {
        af[i] = *(const short8*)&As[(wm * 32 + i * 16 + l16) * 64 + ks * 32 + quad * 8];
        bf[i] = *(const short8*)&Bs[(wn * 32 + i * 16 + l16) * 64 + ks * 32 + quad * 8];
      }
#pragma unroll
      for (int mi = 0; mi < 2; mi++)
#pragma unroll
        for (int ni = 0; ni < 2; ni++)
          acc[mi][ni] = __builtin_amdgcn_mfma_f32_16x16x32_bf16(af[mi], bf[ni], acc[mi][ni], 0, 0, 0);
    }
    __syncthreads();
  }

#pragma unroll
  for (int mi = 0; mi < 2; mi++)
#pragma unroll
    for (int ni = 0; ni < 2; ni++) {
      const int col = n0 + wn * 32 + ni * 16 + l16;
#pragma unroll
      for (int rr = 0; rr < 4; rr++) {
        const int row = m0 + wm * 32 + mi * 16 + quad * 4 + rr;
        Cf[(size_t)row * Nn + col] = acc[mi][ni][rr] + bias[col];
      }
    }
}

// ---- Flash attention: 128 q-rows/block (32/wave), DMA-staged LDS ----
// HALF-dispatch: grid 768 covers slices 0..23 = 12h x 2sp; sp = sp_base + slice/12.
// s8=b%8, slice=s8+8*(j%nsl8), qb=j/nsl8 (0..31); nsl8=3. ntiles=16 (S=4).
// Linear LDS [64][64]; sigma token perm + 16B-unit XOR swizzle on global source;
// reads use u0/u1 swizzled offsets. STAGE(next) -> compute(cur) -> __syncthreads.

#define ATTN_STAGE(bufi)                                                       \
  do {                                                                         \
    async16(&Ks[bufi][(wave * 16) * 64],     kp0);                             \
    async16(&Ks[bufi][(wave * 16 + 8) * 64], kp1);                             \
    async16(&Vs[bufi][(wave * 16) * 64],     vp0);                             \
    async16(&Vs[bufi][(wave * 16 + 8) * 64], vp1);                             \
    kp0 += (size_t)64 * QK_LD; kp1 += (size_t)64 * QK_LD;                      \
    vp0 += 64; vp1 += 64;                                                      \
  } while (0)

#define ATTN_TILE(KbP, VbP)                                                    \
  do {                                                                         \
    const ushort* Kb_ = (KbP);                                                 \
    const ushort* Vb_ = (VbP);                                                 \
    _Pragma("unroll")                                                          \
    for (int ks = 0; ks < 2; ks++) {                                           \
      union { unsigned u[4]; short8 v; } pfu0, pfu1;                           \
      _Pragma("unroll")                                                        \
      for (int h2 = 0; h2 < 2; h2++) {                                         \
        const int nt = 2 * ks + h2;                                            \
        const short8 kf0 = *(const short8*)&Kb_[(nt * 16 + l16) * 64 + u0];    \
        const short8 kf1 = *(const short8*)&Kb_[(nt * 16 + l16) * 64 + u1];    \
        f32x4 a0 = __builtin_amdgcn_mfma_f32_16x16x32_bf16(kf0, qf[0][0], z4, 0, 0, 0); \
        a0 = __builtin_amdgcn_mfma_f32_16x16x32_bf16(kf1, qf[0][1], a0, 0, 0, 0);       \
        f32x4 a1 = __builtin_amdgcn_mfma_f32_16x16x32_bf16(kf0, qf[1][0], z4, 0, 0, 0); \
        a1 = __builtin_amdgcn_mfma_f32_16x16x32_bf16(kf1, qf[1][1], a1, 0, 0, 0);       \
        {                                                                      \
          const float e0 = EXP2F(a0[0]);                                       \
          const float e1 = EXP2F(a0[1]);                                       \
          const float e2 = EXP2F(a0[2]);                                       \
          const float e3 = EXP2F(a0[3]);                                       \
          lsum[0] += (e0 + e1) + (e2 + e3);                                    \
          pfu0.u[2 * h2]     = PACK2BF(__float_as_uint(e1), __float_as_uint(e0)); \
          pfu0.u[2 * h2 + 1] = PACK2BF(__float_as_uint(e3), __float_as_uint(e2)); \
        }                                                                      \
        {                                                                      \
          const float e0 = EXP2F(a1[0]);                                       \
          const float e1 = EXP2F(a1[1]);                                       \
          const float e2 = EXP2F(a1[2]);                                       \
          const float e3 = EXP2F(a1[3]);                                       \
          lsum[1] += (e0 + e1) + (e2 + e3);                                    \
          pfu1.u[2 * h2]     = PACK2BF(__float_as_uint(e1), __float_as_uint(e0)); \
          pfu1.u[2 * h2 + 1] = PACK2BF(__float_as_uint(e3), __float_as_uint(e2)); \
        }                                                                      \
      }                                                                        \
      const short8 pf0 = pfu0.v, pf1 = pfu1.v;                                 \
      _Pragma("unroll")                                                        \
      for (int dt = 0; dt < 4; dt++) {                                         \
        const short8 vf = *(const short8*)&Vb_[(dt * 16 + l16) * 64 + (ks ? u1 : u0)]; \
        o[0][dt] = __builtin_amdgcn_mfma_f32_16x16x32_bf16(pf0, vf, o[0][dt], 0, 0, 0); \
        o[1][dt] = __builtin_amdgcn_mfma_f32_16x16x32_bf16(pf1, vf, o[1][dt], 0, 0, 0); \
      }                                                                        \
    }                                                                          \
  } while (0)

__global__ void __launch_bounds__(256, 4) attn_flash(const ushort* __restrict__ qk,
                                                     const ushort* __restrict__ vtg,
                                                     ushort* __restrict__ pob,
                                                     float* __restrict__ pl,
                                                     int ntiles, int nsl8,
                                                     int sp_base) {
  __shared__ __align__(16) ushort Ks[2][64 * 64];
  __shared__ __align__(16) ushort Vs[2][64 * 64];

  const int b = blockIdx.x;
  const int s8 = b & 7;               // presumed XCD (round-robin dispatch)
  const int j = b >> 3;
  const int slice = s8 + 8 * (j % nsl8);   // 0..23 within this half
  const int qb = j / nsl8;                 // 0..31
  const int h = slice % NHEAD;
  const int sp = sp_base + slice / NHEAD;  // global split index

  const int tid = threadIdx.x;
  const int wave = tid >> 6, lane = tid & 63, quad = lane >> 4, l16 = lane & 15;
  const int q0 = qb * 128 + wave * 32;     // this wave's first q row

  // Q fragments (B-operand). Pre-scaled by log2e/8 in gemm_qkv.
  short8 qf[2][2];
#pragma unroll
  for (int s = 0; s < 2; s++) {
    const ushort* qp = qk + (size_t)(q0 + s * 16 + l16) * QK_LD + h * 64 + quad * 8;
    qf[s][0] = *(const short8*)qp;
    qf[s][1] = *(const short8*)(qp + 32);
  }

  // ---- staging source addresses (linear LDS dest; perm+swizzle on global src) ----
  const int srow = wave * 16 + (lane >> 3);                 // i=0 row (i=1: +8, same &7)
  const int un = (((lane & 7) ^ (lane >> 3)) * 8);          // swizzled unit, ushorts
  const int g0 = ((srow >> 5) << 5) + (((srow >> 2) & 3) << 3) +
                 (((srow >> 4) & 1) << 2) + (srow & 3);     // siginv(srow); +8 rows -> +16
  const int kt0 = sp * ntiles;
  const ushort* kp0 = qk + 768 + h * 64 + un + (size_t)(kt0 * 64 + g0) * QK_LD;
  const ushort* kp1 = kp0 + (size_t)16 * QK_LD;
  const ushort* vp0 = vtg + (size_t)(h * 64 + srow) * N_TOK + kt0 * 64 + un;
  const ushort* vp1 = vp0 + (size_t)8 * N_TOK;

  // read-side swizzled column offsets (row&7 == l16&7 for all 16-row strips)
  const int u0 = (quad ^ (l16 & 7)) * 8;
  const int u1 = u0 ^ 32;

  f32x4 o[2][4] = {};
  float lsum[2] = {};
  const f32x4 z4 = {};   // hoisted zero quad: QK-MFMA C operand, zeroed ONCE

  // prologue: DMA tile kt0 into buf0
  ATTN_STAGE(0);
  __syncthreads();

  for (int kt = 0; kt < ntiles; kt++) {
    if (kt + 1 < ntiles) ATTN_STAGE((kt + 1) & 1);   // fire-and-forget DMA of next
    ATTN_TILE(Ks[kt & 1], Vs[kt & 1]);
    __syncthreads();   // drains vmcnt (stage landed) + lgkm (reads done) -> safe swap
  }

  // ---- epilogue: reduce lsum across quads, redistribute to o's row indexing ----
#pragma unroll
  for (int s = 0; s < 2; s++) {
    float lt = lsum[s];
    lt += __shfl_xor(lt, 16, 64);
    lt += __shfl_xor(lt, 32, 64);          // lt = l for q-row (s*16 + l16)
#pragma unroll
    for (int rr = 0; rr < 4; rr++) {
      const float l = __shfl(lt, quad * 16 + quad * 4 + rr, 64);
      const float inv = 1.f / l;
      const int row = q0 + s * 16 + quad * 4 + rr;
      if (l16 == 0)
        pl[(size_t)(sp * NHEAD + h) * N_TOK + row] = l;
#pragma unroll
      for (int dt = 0; dt < 4; dt++)
        pob[((size_t)sp * N_TOK + row) * DMODEL + h * 64 + dt * 16 + l16] =
            bf16bits(o[s][dt][rr] * inv);
    }
  }
}

// ---- combine S split partials: aout = sum(l_s * o_s) / sum(l_s), bf16 ----
// grid: 786432 ushort4-groups / 256 = 3072 blocks
__global__ void __launch_bounds__(256) combine(const ushort* __restrict__ pob,
                                               const float* __restrict__ pl,
                                               ushort* __restrict__ aout, int S) {
  const int i = blockIdx.x * 256 + threadIdx.x;   // ushort4 index
  const int row = i / (DMODEL / 4);
  const int hd = (i % (DMODEL / 4)) * 4;
  const int h = hd >> 6;
  float lt = 0.f, a0 = 0.f, a1 = 0.f, a2 = 0.f, a3 = 0.f;
  for (int s = 0; s < S; s++) {
    const float l = pl[((size_t)s * NHEAD + h) * N_TOK + row];
    const ushort4 a = *(const ushort4*)&pob[((size_t)s * N_TOK + row) * DMODEL + hd];
    lt += l;
    a0 += l * bf2f(a.x); a1 += l * bf2f(a.y); a2 += l * bf2f(a.z); a3 += l * bf2f(a.w);
  }
  const float inv = 1.f / lt;
  ushort4 r;
  r.x = bf16bits(a0 * inv); r.y = bf16bits(a1 * inv);
  r.z = bf16bits(a2 * inv); r.w = bf16bits(a3 * inv);
  *(ushort4*)&aout[(size_t)row * DMODEL + hd] = r;
}

extern "C" void kernel_launch(void* const* d_in, const int* in_sizes, int n_in,
                              void* d_out, int out_size, void* d_ws, size_t ws_size,
                              hipStream_t stream) {
  const float* x     = (const float*)d_in[0];
  const float* w_qkv = (const float*)d_in[1];
  const float* w_out = (const float*)d_in[2];
  const float* b_out = (const float*)d_in[3];
  float* out = (float*)d_out;

  // ws layout (S=4): pob at 0 (4*6.29 MB; xb/wqkvb alias its head, both dead
  // before attn); then qkb, vtg, woutb, pl. aout aliases qkb.
  const size_t PO_UNIT = 6291456UL;   // 4096*768*2
  const int S = (ws_size >= 4 * PO_UNIT + 20840448UL) ? 4 : 2;
  char* ws = (char*)d_ws;
  ushort* pob   = (ushort*)ws;
  ushort* xb    = (ushort*)ws;                          // [0, 6.29M) dead after gemm1
  ushort* wqkvb = (ushort*)(ws + 6291456UL);            // [6.29M, 9.83M) dead after gemm1
  ushort* qkb   = (ushort*)(ws + (size_t)S * PO_UNIT);
  ushort* vtg   = (ushort*)((char*)qkb + 12582912UL);
  ushort* woutb = (ushort*)((char*)vtg + 6291456UL);
  float*  pl    = (float*)((char*)woutb + 1179648UL);
  ushort* aoutb = qkb;                                  // qkb dead after attn

  // 1) converts (one kernel, 3 ranges: 3072 + 1728 + 576 blocks)
  cvt3<<<5376, 256, 0, stream>>>(x, w_qkv, w_out, xb, wqkvb, woutb);

  // 2) qkv GEMM, 128x96 tiles: grid 24x32 = 768 blocks = exactly 3/CU
  gemm_qkv<<<dim3(24, 32), 256, 0, stream>>>(xb, wqkvb, qkb, vtg);

  // 3) flash attention in TWO half-dispatches (diagnostic: surfaces other
  //    kernels in top-5 + measures inter-dispatch gap via timestamps).
  if (S == 4) {
    attn_flash<<<768, 256, 0, stream>>>(qkb, vtg, pob, pl, 16, 3, 0);  // sp 0,1
    attn_flash<<<768, 256, 0, stream>>>(qkb, vtg, pob, pl, 16, 3, 2);  // sp 2,3
  } else {
    attn_flash<<<768, 256, 0, stream>>>(qkb, vtg, pob, pl, 32, 3, 0);  // sp 0,1
  }

  // 4) combine partials -> aout bf16
  combine<<<3072, 256, 0, stream>>>(pob, pl, aoutb, S);

  // 5) out = aout @ w_out^T + b_out (fp32 out), 64x64 tiles, 768 = 3/CU
  gemm_out<<<dim3(12, 64), 256, 0, stream>>>(aoutb, woutb, out, b_out);
}

// Round 14
// 188.134 us; speedup vs baseline: 1.0394x; 1.0394x over previous
//
#include <hip/hip_runtime.h>

// ClassicalSelfAttention: B=1, N=4096, D=768, H=12, Hd=64, fp32 in/out.
// R23 = R17 EXACTLY (best verified: 189.3us). Final configuration.
// Session summary of verified facts:
//  - attn: 128 q-rows/block (32/wave, 2 q-strips), global_load_lds-staged K/V
//    (sigma perm + 16B XOR swizzle folded into global source), bound-4,
//    S=4 KV-split: 64.8us, MfmaUtil 33%, ~82% combined issue. 2-strip wave is
//    the only decomposition that fits without spill (4-strip needs bound-2).
//  - HIP compiler does NOT preserve reg-prefetch pipelines for plain global
//    loads (R10/R20: MfmaUtil 11%); only global_load_lds+barrier survives.
//  - hipLaunchCooperativeKernel silently no-ops under graph capture (R18).
//  - Dispatch-boundary cost ~3-6us each (R22 split experiment).
//  - Uniform 3 blocks/CU fills: gemm_qkv 128x96 grid(24,32)=768 (R17, -8us),
//    gemm_out 64^2 grid(12,64)=768 (R15). S=2/BK=128 regressed (R21).

typedef __attribute__((ext_vector_type(8))) short short8;   // 8 x bf16 fragment
typedef __attribute__((ext_vector_type(4))) float f32x4;    // MFMA accumulator

#define N_TOK 4096
#define NHEAD 12
#define DMODEL 768
#define QK_LD 1536

#if defined(__has_builtin)
#if __has_builtin(__builtin_amdgcn_exp2f)
#define EXP2F __builtin_amdgcn_exp2f
#else
#define EXP2F exp2f
#endif
#else
#define EXP2F exp2f
#endif

#if defined(__has_builtin)
#if __has_builtin(__builtin_amdgcn_perm)
#define PACK2BF(hi, lo) __builtin_amdgcn_perm((hi), (lo), 0x07060302u)
#else
#define PACK2BF(hi, lo) ((((hi)) & 0xffff0000u) | (((lo)) >> 16))
#endif
#else
#define PACK2BF(hi, lo) ((((hi)) & 0xffff0000u) | (((lo)) >> 16))
#endif

__device__ __forceinline__ ushort bf16bits(float x) {
  union { float f; unsigned u; } cv; cv.f = x;
  unsigned u = cv.u;
  u += 0x7fffu + ((u >> 16) & 1u);   // RNE
  return (ushort)(u >> 16);
}
__device__ __forceinline__ float bf2f(ushort u) {
  return __uint_as_float(((unsigned)u) << 16);
}

// async global->LDS, 16 B per lane; lds base must be wave-uniform, HW scatters lane*16.
__device__ __forceinline__ void async16(ushort* lds, const ushort* g) {
  __builtin_amdgcn_global_load_lds((const __attribute__((address_space(1))) unsigned int*)g,
                                   (__attribute__((address_space(3))) unsigned int*)lds,
                                   16, 0, 0);
}

// ---- fused fp32->bf16 converts for x (3072 blk), w_qkv (1728 blk), w_out (576 blk) ----
__global__ void __launch_bounds__(256) cvt3(const float* __restrict__ x,
                                            const float* __restrict__ wq,
                                            const float* __restrict__ wo,
                                            ushort* __restrict__ xb,
                                            ushort* __restrict__ wqb,
                                            ushort* __restrict__ wob) {
  const int b = blockIdx.x, t = threadIdx.x;
  const float* src; ushort* dst; int i;
  if (b < 3072)      { src = x;  dst = xb;  i = b * 256 + t; }           // 786432 f4
  else if (b < 4800) { src = wq; dst = wqb; i = (b - 3072) * 256 + t; }  // 442368 f4
  else               { src = wo; dst = wob; i = (b - 4800) * 256 + t; }  // 147456 f4
  const float4 v = ((const float4*)src)[i];
  ushort4 o;
  o.x = bf16bits(v.x); o.y = bf16bits(v.y); o.z = bf16bits(v.z); o.w = bf16bits(v.w);
  ((ushort4*)dst)[i] = o;
}

#define GEMM_STAGE(Ms, Mp, MK)                                                 \
  do {                                                                         \
    _Pragma("unroll")                                                          \
    for (int i_ = 0; i_ < 4; i_++)                                             \
      async16(&Ms[(wave * 32 + i_ * 8) * 64],                                  \
              Mp + (size_t)(wave * 32 + i_ * 8 + lrow) * (MK) + lcol);         \
  } while (0)

#define GEMM_STAGE96(Ms, Mp, MK)                                               \
  do {                                                                         \
    _Pragma("unroll")                                                          \
    for (int i_ = 0; i_ < 3; i_++)                                             \
      async16(&Ms[(wave * 24 + i_ * 8) * 64],                                  \
              Mp + (size_t)(wave * 24 + i_ * 8 + lrow) * (MK) + lcol);         \
  } while (0)

#define GEMM_STAGE64(Ms, Mp, MK)                                               \
  do {                                                                         \
    _Pragma("unroll")                                                          \
    for (int i_ = 0; i_ < 2; i_++)                                             \
      async16(&Ms[(wave * 16 + i_ * 8) * 64],                                  \
              Mp + (size_t)(wave * 16 + i_ * 8 + lrow) * (MK) + lcol);         \
  } while (0)

// ---- GEMM1: qkv = x @ w_qkv^T.  128x96 tiles, grid 24x32 = 768 = 3/CU exact.
//      Q cols pre-scaled by log2e/8 -> qk[n][1536]; V cols -> vtg[h*64+d][n].
__global__ void __launch_bounds__(256) gemm_qkv(const ushort* __restrict__ A,
                                                const ushort* __restrict__ B,
                                                ushort* __restrict__ qkb,
                                                ushort* __restrict__ vtg) {
  __shared__ __align__(16) ushort As[128 * 64];
  __shared__ __align__(16) ushort Bs[96 * 64];
  const int tid = threadIdx.x;
  const int wave = tid >> 6, lane = tid & 63, quad = lane >> 4, l16 = lane & 15;
  const int wm = wave & 1, wn = wave >> 1;     // 2x2 waves: 64-row x 48-col tiles
  const int lrow = lane >> 3, lcol = (lane & 7) * 8;
  const int m0 = blockIdx.y * 128, n0 = blockIdx.x * 96;
  const int K = DMODEL;

  f32x4 acc[4][3] = {};
  const ushort* Ap = A + (size_t)m0 * K;
  const ushort* Bp = B + (size_t)n0 * K;

  for (int k0 = 0; k0 < K; k0 += 64) {
    GEMM_STAGE(As, Ap + k0, K);
    GEMM_STAGE96(Bs, Bp + k0, K);
    __syncthreads();   // drains vmcnt -> staged data visible
#pragma unroll
    for (int ks = 0; ks < 2; ks++) {
      short8 af[4], bf[3];
#pragma unroll
      for (int i = 0; i < 4; i++)
        af[i] = *(const short8*)&As[(wm * 64 + i * 16 + l16) * 64 + ks * 32 + quad * 8];
#pragma unroll
      for (int i = 0; i < 3; i++)
        bf[i] = *(const short8*)&Bs[(wn * 48 + i * 16 + l16) * 64 + ks * 32 + quad * 8];
#pragma unroll
      for (int mi = 0; mi < 4; mi++)
#pragma unroll
        for (int ni = 0; ni < 3; ni++)
          acc[mi][ni] = __builtin_amdgcn_mfma_f32_16x16x32_bf16(af[mi], bf[ni], acc[mi][ni], 0, 0, 0);
    }
    __syncthreads();
  }

  if (n0 < QK_LD) {
    // Q/K epilogue (tiles never straddle 768: 768/96 = 8 blocks exactly).
    const float qsc = (n0 < 768) ? 0.18033688011112042f : 1.0f;  // log2(e)/8
#pragma unroll
    for (int mi = 0; mi < 4; mi++)
#pragma unroll
      for (int ni = 0; ni < 3; ni++) {
        const int col = n0 + wn * 48 + ni * 16 + l16;
#pragma unroll
        for (int rr = 0; rr < 4; rr++) {
          const int row = m0 + wm * 64 + mi * 16 + quad * 4 + rr;
          qkb[(size_t)row * QK_LD + col] = bf16bits(acc[mi][ni][rr] * qsc);
        }
      }
  } else {
    // V epilogue: vtg[col-1536][row], 4 consecutive rows packed per lane.
#pragma unroll
    for (int mi = 0; mi < 4; mi++)
#pragma unroll
      for (int ni = 0; ni < 3; ni++) {
        const int col = n0 + wn * 48 + ni * 16 + l16 - QK_LD;   // = h*64+d
        const int rowb = m0 + wm * 64 + mi * 16 + quad * 4;
        const unsigned u0 = (unsigned)bf16bits(acc[mi][ni][0]) |
                            ((unsigned)bf16bits(acc[mi][ni][1]) << 16);
        const unsigned u1 = (unsigned)bf16bits(acc[mi][ni][2]) |
                            ((unsigned)bf16bits(acc[mi][ni][3]) << 16);
        *(uint2*)&vtg[(size_t)col * N_TOK + rowb] = make_uint2(u0, u1);
      }
  }
}

// ---- GEMM2: out = aout @ w_out^T + bias (fp32 out), 64x64 tiles ----
// grid dim3(12,64) = 768 blocks = exactly 3/CU. 4 waves as 2x2, wave tile 32x32.
__global__ void __launch_bounds__(256) gemm_out(const ushort* __restrict__ A,
                                                const ushort* __restrict__ B,
                                                float* __restrict__ Cf,
                                                const float* __restrict__ bias) {
  __shared__ __align__(16) ushort As[64 * 64];
  __shared__ __align__(16) ushort Bs[64 * 64];
  const int tid = threadIdx.x;
  const int wave = tid >> 6, lane = tid & 63, quad = lane >> 4, l16 = lane & 15;
  const int wm = wave & 1, wn = wave >> 1;
  const int lrow = lane >> 3, lcol = (lane & 7) * 8;
  const int m0 = blockIdx.y * 64, n0 = blockIdx.x * 64;
  const int K = DMODEL, Nn = DMODEL;

  f32x4 acc[2][2] = {};
  const ushort* Ap = A + (size_t)m0 * K;
  const ushort* Bp = B + (size_t)n0 * K;

  for (int k0 = 0; k0 < K; k0 += 64) {
    GEMM_STAGE64(As, Ap + k0, K);
    GEMM_STAGE64(Bs, Bp + k0, K);
    __syncthreads();
#pragma unroll
    for (int ks = 0; ks < 2; ks++) {
      short8 af[2], bf[2];
#pragma unroll
      for (int i = 0; i < 2; i++) {
        af[i] = *(const short8*)&As[(wm * 32 + i * 16 + l16) * 64 + ks * 32 + quad * 8];
        bf[i] = *(const short8*)&Bs[(wn * 32 + i * 16 + l16) * 64 + ks * 32 + quad * 8];
      }
#pragma unroll
      for (int mi = 0; mi < 2; mi++)
#pragma unroll
        for (int ni = 0; ni < 2; ni++)
          acc[mi][ni] = __builtin_amdgcn_mfma_f32_16x16x32_bf16(af[mi], bf[ni], acc[mi][ni], 0, 0, 0);
    }
    __syncthreads();
  }

#pragma unroll
  for (int mi = 0; mi < 2; mi++)
#pragma unroll
    for (int ni = 0; ni < 2; ni++) {
      const int col = n0 + wn * 32 + ni * 16 + l16;
#pragma unroll
      for (int rr = 0; rr < 4; rr++) {
        const int row = m0 + wm * 32 + mi * 16 + quad * 4 + rr;
        Cf[(size_t)row * Nn + col] = acc[mi][ni][rr] + bias[col];
      }
    }
}

// ---- Flash attention: 128 q-rows/block (32/wave), DMA-staged LDS, KV-split-S ----
// Grid 384*S (1D). XCD swizzle: s8=b%8, slice=s8+8*(j%nsl8), qb=j/nsl8 (0..31);
// h=slice%12, sp=slice/12. ntiles = 64/S covers ALL KV tiles.
// Linear LDS [64][64]; sigma token perm + 16B-unit XOR swizzle (unit ^= row&7)
// pre-applied to the GLOBAL source address; reads use u0/u1 swizzled offsets
// (2-way bank alias = free). STAGE(next) fire-and-forget -> compute(cur) ->
// __syncthreads (vm+lgkm drain).

#define ATTN_STAGE(bufi)                                                       \
  do {                                                                         \
    async16(&Ks[bufi][(wave * 16) * 64],     kp0);                             \
    async16(&Ks[bufi][(wave * 16 + 8) * 64], kp1);                             \
    async16(&Vs[bufi][(wave * 16) * 64],     vp0);                             \
    async16(&Vs[bufi][(wave * 16 + 8) * 64], vp1);                             \
    kp0 += (size_t)64 * QK_LD; kp1 += (size_t)64 * QK_LD;                      \
    vp0 += 64; vp1 += 64;                                                      \
  } while (0)

// Windowed tile (2 q-strips): QK MFMAs take z4 (hoisted zero quad) as C; exp2
// results pack directly into named pfu0/pfu1 unions.
#define ATTN_TILE(KbP, VbP)                                                    \
  do {                                                                         \
    const ushort* Kb_ = (KbP);                                                 \
    const ushort* Vb_ = (VbP);                                                 \
    _Pragma("unroll")                                                          \
    for (int ks = 0; ks < 2; ks++) {                                           \
      union { unsigned u[4]; short8 v; } pfu0, pfu1;                           \
      _Pragma("unroll")                                                        \
      for (int h2 = 0; h2 < 2; h2++) {                                         \
        const int nt = 2 * ks + h2;                                            \
        const short8 kf0 = *(const short8*)&Kb_[(nt * 16 + l16) * 64 + u0];    \
        const short8 kf1 = *(const short8*)&Kb_[(nt * 16 + l16) * 64 + u1];    \
        f32x4 a0 = __builtin_amdgcn_mfma_f32_16x16x32_bf16(kf0, qf[0][0], z4, 0, 0, 0); \
        a0 = __builtin_amdgcn_mfma_f32_16x16x32_bf16(kf1, qf[0][1], a0, 0, 0, 0);       \
        f32x4 a1 = __builtin_amdgcn_mfma_f32_16x16x32_bf16(kf0, qf[1][0], z4, 0, 0, 0); \
        a1 = __builtin_amdgcn_mfma_f32_16x16x32_bf16(kf1, qf[1][1], a1, 0, 0, 0);       \
        {                                                                      \
          const float e0 = EXP2F(a0[0]);                                       \
          const float e1 = EXP2F(a0[1]);                                       \
          const float e2 = EXP2F(a0[2]);                                       \
          const float e3 = EXP2F(a0[3]);                                       \
          lsum[0] += (e0 + e1) + (e2 + e3);                                    \
          pfu0.u[2 * h2]     = PACK2BF(__float_as_uint(e1), __float_as_uint(e0)); \
          pfu0.u[2 * h2 + 1] = PACK2BF(__float_as_uint(e3), __float_as_uint(e2)); \
        }                                                                      \
        {                                                                      \
          const float e0 = EXP2F(a1[0]);                                       \
          const float e1 = EXP2F(a1[1]);                                       \
          const float e2 = EXP2F(a1[2]);                                       \
          const float e3 = EXP2F(a1[3]);                                       \
          lsum[1] += (e0 + e1) + (e2 + e3);                                    \
          pfu1.u[2 * h2]     = PACK2BF(__float_as_uint(e1), __float_as_uint(e0)); \
          pfu1.u[2 * h2 + 1] = PACK2BF(__float_as_uint(e3), __float_as_uint(e2)); \
        }                                                                      \
      }                                                                        \
      const short8 pf0 = pfu0.v, pf1 = pfu1.v;                                 \
      _Pragma("unroll")                                                        \
      for (int dt = 0; dt < 4; dt++) {                                         \
        const short8 vf = *(const short8*)&Vb_[(dt * 16 + l16) * 64 + (ks ? u1 : u0)]; \
        o[0][dt] = __builtin_amdgcn_mfma_f32_16x16x32_bf16(pf0, vf, o[0][dt], 0, 0, 0); \
        o[1][dt] = __builtin_amdgcn_mfma_f32_16x16x32_bf16(pf1, vf, o[1][dt], 0, 0, 0); \
      }                                                                        \
    }                                                                          \
  } while (0)

__global__ void __launch_bounds__(256, 4) attn_flash(const ushort* __restrict__ qk,
                                                     const ushort* __restrict__ vtg,
                                                     ushort* __restrict__ pob,
                                                     float* __restrict__ pl,
                                                     int ntiles, int nsl8) {
  __shared__ __align__(16) ushort Ks[2][64 * 64];
  __shared__ __align__(16) ushort Vs[2][64 * 64];

  const int b = blockIdx.x;
  const int s8 = b & 7;               // presumed XCD (round-robin dispatch)
  const int j = b >> 3;
  const int slice = s8 + 8 * (j % nsl8);   // 0..12*S-1, pinned to XCD s8
  const int qb = j / nsl8;                 // 0..31
  const int h = slice % NHEAD;
  const int sp = slice / NHEAD;            // 0..S-1

  const int tid = threadIdx.x;
  const int wave = tid >> 6, lane = tid & 63, quad = lane >> 4, l16 = lane & 15;
  const int q0 = qb * 128 + wave * 32;     // this wave's first q row

  // Q fragments (B-operand: q = l16 within strip, k = quad*8+j). Pre-scaled by log2e/8.
  short8 qf[2][2];
#pragma unroll
  for (int s = 0; s < 2; s++) {
    const ushort* qp = qk + (size_t)(q0 + s * 16 + l16) * QK_LD + h * 64 + quad * 8;
    qf[s][0] = *(const short8*)qp;
    qf[s][1] = *(const short8*)(qp + 32);
  }

  // ---- staging source addresses (linear LDS dest; perm+swizzle on global src) ----
  const int srow = wave * 16 + (lane >> 3);                 // i=0 row (i=1: +8, same &7)
  const int un = (((lane & 7) ^ (lane >> 3)) * 8);          // swizzled unit, ushorts
  const int g0 = ((srow >> 5) << 5) + (((srow >> 2) & 3) << 3) +
                 (((srow >> 4) & 1) << 2) + (srow & 3);     // siginv(srow); +8 rows -> +16
  const int kt0 = sp * ntiles;
  const ushort* kp0 = qk + 768 + h * 64 + un + (size_t)(kt0 * 64 + g0) * QK_LD;
  const ushort* kp1 = kp0 + (size_t)16 * QK_LD;
  const ushort* vp0 = vtg + (size_t)(h * 64 + srow) * N_TOK + kt0 * 64 + un;
  const ushort* vp1 = vp0 + (size_t)8 * N_TOK;

  // read-side swizzled column offsets (row&7 == l16&7 for all 16-row strips)
  const int u0 = (quad ^ (l16 & 7)) * 8;
  const int u1 = u0 ^ 32;

  f32x4 o[2][4] = {};
  float lsum[2] = {};
  const f32x4 z4 = {};   // hoisted zero quad: QK-MFMA C operand, zeroed ONCE

  // prologue: DMA tile kt0 into buf0
  ATTN_STAGE(0);
  __syncthreads();

  for (int kt = 0; kt < ntiles; kt++) {
    if (kt + 1 < ntiles) ATTN_STAGE((kt + 1) & 1);   // fire-and-forget DMA of next
    ATTN_TILE(Ks[kt & 1], Vs[kt & 1]);
    __syncthreads();   // drains vmcnt (stage landed) + lgkm (reads done) -> safe swap
  }

  // ---- epilogue: reduce lsum across quads, redistribute to o's row indexing ----
#pragma unroll
  for (int s = 0; s < 2; s++) {
    float lt = lsum[s];
    lt += __shfl_xor(lt, 16, 64);
    lt += __shfl_xor(lt, 32, 64);          // lt = l for q-row (s*16 + l16)
#pragma unroll
    for (int rr = 0; rr < 4; rr++) {
      const float l = __shfl(lt, quad * 16 + quad * 4 + rr, 64);
      const float inv = 1.f / l;
      const int row = q0 + s * 16 + quad * 4 + rr;
      if (l16 == 0)
        pl[(size_t)(sp * NHEAD + h) * N_TOK + row] = l;
#pragma unroll
      for (int dt = 0; dt < 4; dt++)
        pob[((size_t)sp * N_TOK + row) * DMODEL + h * 64 + dt * 16 + l16] =
            bf16bits(o[s][dt][rr] * inv);
    }
  }
}

// ---- combine S split partials: aout = sum(l_s * o_s) / sum(l_s), bf16 ----
// grid: 786432 ushort4-groups / 256 = 3072 blocks
__global__ void __launch_bounds__(256) combine(const ushort* __restrict__ pob,
                                               const float* __restrict__ pl,
                                               ushort* __restrict__ aout, int S) {
  const int i = blockIdx.x * 256 + threadIdx.x;   // ushort4 index
  const int row = i / (DMODEL / 4);
  const int hd = (i % (DMODEL / 4)) * 4;
  const int h = hd >> 6;
  float lt = 0.f, a0 = 0.f, a1 = 0.f, a2 = 0.f, a3 = 0.f;
  for (int s = 0; s < S; s++) {
    const float l = pl[((size_t)s * NHEAD + h) * N_TOK + row];
    const ushort4 a = *(const ushort4*)&pob[((size_t)s * N_TOK + row) * DMODEL + hd];
    lt += l;
    a0 += l * bf2f(a.x); a1 += l * bf2f(a.y); a2 += l * bf2f(a.z); a3 += l * bf2f(a.w);
  }
  const float inv = 1.f / lt;
  ushort4 r;
  r.x = bf16bits(a0 * inv); r.y = bf16bits(a1 * inv);
  r.z = bf16bits(a2 * inv); r.w = bf16bits(a3 * inv);
  *(ushort4*)&aout[(size_t)row * DMODEL + hd] = r;
}

extern "C" void kernel_launch(void* const* d_in, const int* in_sizes, int n_in,
                              void* d_out, int out_size, void* d_ws, size_t ws_size,
                              hipStream_t stream) {
  const float* x     = (const float*)d_in[0];
  const float* w_qkv = (const float*)d_in[1];
  const float* w_out = (const float*)d_in[2];
  const float* b_out = (const float*)d_in[3];
  float* out = (float*)d_out;

  // ws layout (runtime split count S): pob at 0 (S*6.29 MB; xb/wqkvb alias its
  // head, both dead before attn); then qkb, vtg, woutb, pl. aout aliases qkb.
  const size_t PO_UNIT = 6291456UL;   // 4096*768*2
  const int S = (ws_size >= 4 * PO_UNIT + 20840448UL) ? 4 : 2;
  char* ws = (char*)d_ws;
  ushort* pob   = (ushort*)ws;
  ushort* xb    = (ushort*)ws;                          // [0, 6.29M) dead after gemm1
  ushort* wqkvb = (ushort*)(ws + 6291456UL);            // [6.29M, 9.83M) dead after gemm1
  ushort* qkb   = (ushort*)(ws + (size_t)S * PO_UNIT);
  ushort* vtg   = (ushort*)((char*)qkb + 12582912UL);
  ushort* woutb = (ushort*)((char*)vtg + 6291456UL);
  float*  pl    = (float*)((char*)woutb + 1179648UL);
  ushort* aoutb = qkb;                                  // qkb dead after attn

  // 1) converts (one kernel, 3 ranges: 3072 + 1728 + 576 blocks)
  cvt3<<<5376, 256, 0, stream>>>(x, w_qkv, w_out, xb, wqkvb, woutb);

  // 2) qkv GEMM, 128x96 tiles: grid 24x32 = 768 blocks = exactly 3/CU
  gemm_qkv<<<dim3(24, 32), 256, 0, stream>>>(xb, wqkvb, qkb, vtg);

  // 3) flash attention (128 q-rows/block, KV-split-S over ALL 64 tiles: ntiles=64/S)
  attn_flash<<<384 * S, 256, 0, stream>>>(qkb, vtg, pob, pl, 64 / S, (12 * S) / 8);

  // 4) combine partials -> aout bf16
  combine<<<3072, 256, 0, stream>>>(pob, pl, aoutb, S);

  // 5) out = aout @ w_out^T + b_out (fp32 out), 64x64 tiles, 768 blocks = 3/CU
  gemm_out<<<dim3(12, 64), 256, 0, stream>>>(aoutb, woutb, out, b_out);
}

// Round 15
// 187.134 us; speedup vs baseline: 1.0449x; 1.0053x over previous
//
#include <hip/hip_runtime.h>

// ClassicalSelfAttention: B=1, N=4096, D=768, H=12, Hd=64, fp32 in/out.
// R24 = R23 (verified 188.1us) with ONE lever: attn triple-buffer + counted
// vmcnt barrier (T3/T4). __syncthreads forces vmcnt(0) -> every wave waits for
// the in-flight next-tile DMA. With 3 LDS buffer pairs, stage(kt+2) is issued
// at iter kt and the barrier only needs stage(kt+1) complete: inline
// "s_waitcnt vmcnt(4) lgkmcnt(0); s_barrier" leaves the 4 newest DMA ops in
// flight across the barrier (never drains to 0 mid-loop; tail iters use 0).
// Safety: stage(kt+2) targets buf[(kt-1)%3] whose reads drained at the kt-1
// barrier (lgkmcnt(0)); vmcnt(4) = exactly the 4 younger ops. LDS 48KB ->
// 3 blocks/CU, grid 1536 = 2 exact fills. Falsifiers: absmax != 0.00195 =
// race -> revert; WRITE > 30MB = spill -> revert; total > 190 -> revert.
// All other kernels byte-identical to R23/R17.

typedef __attribute__((ext_vector_type(8))) short short8;   // 8 x bf16 fragment
typedef __attribute__((ext_vector_type(4))) float f32x4;    // MFMA accumulator

#define N_TOK 4096
#define NHEAD 12
#define DMODEL 768
#define QK_LD 1536

#if defined(__has_builtin)
#if __has_builtin(__builtin_amdgcn_exp2f)
#define EXP2F __builtin_amdgcn_exp2f
#else
#define EXP2F exp2f
#endif
#else
#define EXP2F exp2f
#endif

#if defined(__has_builtin)
#if __has_builtin(__builtin_amdgcn_perm)
#define PACK2BF(hi, lo) __builtin_amdgcn_perm((hi), (lo), 0x07060302u)
#else
#define PACK2BF(hi, lo) ((((hi)) & 0xffff0000u) | (((lo)) >> 16))
#endif
#else
#define PACK2BF(hi, lo) ((((hi)) & 0xffff0000u) | (((lo)) >> 16))
#endif

__device__ __forceinline__ ushort bf16bits(float x) {
  union { float f; unsigned u; } cv; cv.f = x;
  unsigned u = cv.u;
  u += 0x7fffu + ((u >> 16) & 1u);   // RNE
  return (ushort)(u >> 16);
}
__device__ __forceinline__ float bf2f(ushort u) {
  return __uint_as_float(((unsigned)u) << 16);
}

// async global->LDS, 16 B per lane; lds base must be wave-uniform, HW scatters lane*16.
__device__ __forceinline__ void async16(ushort* lds, const ushort* g) {
  __builtin_amdgcn_global_load_lds((const __attribute__((address_space(1))) unsigned int*)g,
                                   (__attribute__((address_space(3))) unsigned int*)lds,
                                   16, 0, 0);
}

// ---- fused fp32->bf16 converts for x (3072 blk), w_qkv (1728 blk), w_out (576 blk) ----
__global__ void __launch_bounds__(256) cvt3(const float* __restrict__ x,
                                            const float* __restrict__ wq,
                                            const float* __restrict__ wo,
                                            ushort* __restrict__ xb,
                                            ushort* __restrict__ wqb,
                                            ushort* __restrict__ wob) {
  const int b = blockIdx.x, t = threadIdx.x;
  const float* src; ushort* dst; int i;
  if (b < 3072)      { src = x;  dst = xb;  i = b * 256 + t; }           // 786432 f4
  else if (b < 4800) { src = wq; dst = wqb; i = (b - 3072) * 256 + t; }  // 442368 f4
  else               { src = wo; dst = wob; i = (b - 4800) * 256 + t; }  // 147456 f4
  const float4 v = ((const float4*)src)[i];
  ushort4 o;
  o.x = bf16bits(v.x); o.y = bf16bits(v.y); o.z = bf16bits(v.z); o.w = bf16bits(v.w);
  ((ushort4*)dst)[i] = o;
}

#define GEMM_STAGE(Ms, Mp, MK)                                                 \
  do {                                                                         \
    _Pragma("unroll")                                                          \
    for (int i_ = 0; i_ < 4; i_++)                                             \
      async16(&Ms[(wave * 32 + i_ * 8) * 64],                                  \
              Mp + (size_t)(wave * 32 + i_ * 8 + lrow) * (MK) + lcol);         \
  } while (0)

#define GEMM_STAGE96(Ms, Mp, MK)                                               \
  do {                                                                         \
    _Pragma("unroll")                                                          \
    for (int i_ = 0; i_ < 3; i_++)                                             \
      async16(&Ms[(wave * 24 + i_ * 8) * 64],                                  \
              Mp + (size_t)(wave * 24 + i_ * 8 + lrow) * (MK) + lcol);         \
  } while (0)

#define GEMM_STAGE64(Ms, Mp, MK)                                               \
  do {                                                                         \
    _Pragma("unroll")                                                          \
    for (int i_ = 0; i_ < 2; i_++)                                             \
      async16(&Ms[(wave * 16 + i_ * 8) * 64],                                  \
              Mp + (size_t)(wave * 16 + i_ * 8 + lrow) * (MK) + lcol);         \
  } while (0)

// ---- GEMM1: qkv = x @ w_qkv^T.  128x96 tiles, grid 24x32 = 768 = 3/CU exact.
__global__ void __launch_bounds__(256) gemm_qkv(const ushort* __restrict__ A,
                                                const ushort* __restrict__ B,
                                                ushort* __restrict__ qkb,
                                                ushort* __restrict__ vtg) {
  __shared__ __align__(16) ushort As[128 * 64];
  __shared__ __align__(16) ushort Bs[96 * 64];
  const int tid = threadIdx.x;
  const int wave = tid >> 6, lane = tid & 63, quad = lane >> 4, l16 = lane & 15;
  const int wm = wave & 1, wn = wave >> 1;
  const int lrow = lane >> 3, lcol = (lane & 7) * 8;
  const int m0 = blockIdx.y * 128, n0 = blockIdx.x * 96;
  const int K = DMODEL;

  f32x4 acc[4][3] = {};
  const ushort* Ap = A + (size_t)m0 * K;
  const ushort* Bp = B + (size_t)n0 * K;

  for (int k0 = 0; k0 < K; k0 += 64) {
    GEMM_STAGE(As, Ap + k0, K);
    GEMM_STAGE96(Bs, Bp + k0, K);
    __syncthreads();   // drains vmcnt -> staged data visible
#pragma unroll
    for (int ks = 0; ks < 2; ks++) {
      short8 af[4], bf[3];
#pragma unroll
      for (int i = 0; i < 4; i++)
        af[i] = *(const short8*)&As[(wm * 64 + i * 16 + l16) * 64 + ks * 32 + quad * 8];
#pragma unroll
      for (int i = 0; i < 3; i++)
        bf[i] = *(const short8*)&Bs[(wn * 48 + i * 16 + l16) * 64 + ks * 32 + quad * 8];
#pragma unroll
      for (int mi = 0; mi < 4; mi++)
#pragma unroll
        for (int ni = 0; ni < 3; ni++)
          acc[mi][ni] = __builtin_amdgcn_mfma_f32_16x16x32_bf16(af[mi], bf[ni], acc[mi][ni], 0, 0, 0);
    }
    __syncthreads();
  }

  if (n0 < QK_LD) {
    const float qsc = (n0 < 768) ? 0.18033688011112042f : 1.0f;  // log2(e)/8
#pragma unroll
    for (int mi = 0; mi < 4; mi++)
#pragma unroll
      for (int ni = 0; ni < 3; ni++) {
        const int col = n0 + wn * 48 + ni * 16 + l16;
#pragma unroll
        for (int rr = 0; rr < 4; rr++) {
          const int row = m0 + wm * 64 + mi * 16 + quad * 4 + rr;
          qkb[(size_t)row * QK_LD + col] = bf16bits(acc[mi][ni][rr] * qsc);
        }
      }
  } else {
#pragma unroll
    for (int mi = 0; mi < 4; mi++)
#pragma unroll
      for (int ni = 0; ni < 3; ni++) {
        const int col = n0 + wn * 48 + ni * 16 + l16 - QK_LD;   // = h*64+d
        const int rowb = m0 + wm * 64 + mi * 16 + quad * 4;
        const unsigned u0 = (unsigned)bf16bits(acc[mi][ni][0]) |
                            ((unsigned)bf16bits(acc[mi][ni][1]) << 16);
        const unsigned u1 = (unsigned)bf16bits(acc[mi][ni][2]) |
                            ((unsigned)bf16bits(acc[mi][ni][3]) << 16);
        *(uint2*)&vtg[(size_t)col * N_TOK + rowb] = make_uint2(u0, u1);
      }
  }
}

// ---- GEMM2: out = aout @ w_out^T + bias (fp32 out), 64x64 tiles, 768 = 3/CU ----
__global__ void __launch_bounds__(256) gemm_out(const ushort* __restrict__ A,
                                                const ushort* __restrict__ B,
                                                float* __restrict__ Cf,
                                                const float* __restrict__ bias) {
  __shared__ __align__(16) ushort As[64 * 64];
  __shared__ __align__(16) ushort Bs[64 * 64];
  const int tid = threadIdx.x;
  const int wave = tid >> 6, lane = tid & 63, quad = lane >> 4, l16 = lane & 15;
  const int wm = wave & 1, wn = wave >> 1;
  const int lrow = lane >> 3, lcol = (lane & 7) * 8;
  const int m0 = blockIdx.y * 64, n0 = blockIdx.x * 64;
  const int K = DMODEL, Nn = DMODEL;

  f32x4 acc[2][2] = {};
  const ushort* Ap = A + (size_t)m0 * K;
  const ushort* Bp = B + (size_t)n0 * K;

  for (int k0 = 0; k0 < K; k0 += 64) {
    GEMM_STAGE64(As, Ap + k0, K);
    GEMM_STAGE64(Bs, Bp + k0, K);
    __syncthreads();
#pragma unroll
    for (int ks = 0; ks < 2; ks++) {
      short8 af[2], bf[2];
#pragma unroll
      for (int i = 0; i < 2; i++) {
        af[i] = *(const short8*)&As[(wm * 32 + i * 16 + l16) * 64 + ks * 32 + quad * 8];
        bf[i] = *(const short8*)&Bs[(wn * 32 + i * 16 + l16) * 64 + ks * 32 + quad * 8];
      }
#pragma unroll
      for (int mi = 0; mi < 2; mi++)
#pragma unroll
        for (int ni = 0; ni < 2; ni++)
          acc[mi][ni] = __builtin_amdgcn_mfma_f32_16x16x32_bf16(af[mi], bf[ni], acc[mi][ni], 0, 0, 0);
    }
    __syncthreads();
  }

#pragma unroll
  for (int mi = 0; mi < 2; mi++)
#pragma unroll
    for (int ni = 0; ni < 2; ni++) {
      const int col = n0 + wn * 32 + ni * 16 + l16;
#pragma unroll
      for (int rr = 0; rr < 4; rr++) {
        const int row = m0 + wm * 32 + mi * 16 + quad * 4 + rr;
        Cf[(size_t)row * Nn + col] = acc[mi][ni][rr] + bias[col];
      }
    }
}

// ---- Flash attention: 128 q-rows/block (32/wave), triple-buffered DMA LDS ----
// Counted-vmcnt barriers: stage(kt+2) in flight across the barrier; only
// stage(kt+1) (issued a full iteration earlier) must have landed.
// Per wave a stage = 4 async16 -> vmcnt(4) leaves exactly the newest stage
// outstanding. lgkmcnt(0) drains this wave's LDS reads of buf[kt%3] before
// the (kt+1)-iteration stage overwrites that buffer. Tail iters: vmcnt(0).

#define ATTN_STAGE(bufi)                                                       \
  do {                                                                         \
    async16(&Ks[bufi][(wave * 16) * 64],     kp0);                             \
    async16(&Ks[bufi][(wave * 16 + 8) * 64], kp1);                             \
    async16(&Vs[bufi][(wave * 16) * 64],     vp0);                             \
    async16(&Vs[bufi][(wave * 16 + 8) * 64], vp1);                             \
    kp0 += (size_t)64 * QK_LD; kp1 += (size_t)64 * QK_LD;                      \
    vp0 += 64; vp1 += 64;                                                      \
  } while (0)

#define WAITBAR4()                                                             \
  do {                                                                         \
    asm volatile("s_waitcnt vmcnt(4) lgkmcnt(0)" ::: "memory");                \
    __builtin_amdgcn_s_barrier();                                              \
  } while (0)

#define WAITBAR0()                                                             \
  do {                                                                         \
    asm volatile("s_waitcnt vmcnt(0) lgkmcnt(0)" ::: "memory");                \
    __builtin_amdgcn_s_barrier();                                              \
  } while (0)

// Windowed tile (2 q-strips): QK MFMAs take z4 (hoisted zero quad) as C; exp2
// results pack directly into named pfu0/pfu1 unions.
#define ATTN_TILE(KbP, VbP)                                                    \
  do {                                                                         \
    const ushort* Kb_ = (KbP);                                                 \
    const ushort* Vb_ = (VbP);                                                 \
    _Pragma("unroll")                                                          \
    for (int ks = 0; ks < 2; ks++) {                                           \
      union { unsigned u[4]; short8 v; } pfu0, pfu1;                           \
      _Pragma("unroll")                                                        \
      for (int h2 = 0; h2 < 2; h2++) {                                         \
        const int nt = 2 * ks + h2;                                            \
        const short8 kf0 = *(const short8*)&Kb_[(nt * 16 + l16) * 64 + u0];    \
        const short8 kf1 = *(const short8*)&Kb_[(nt * 16 + l16) * 64 + u1];    \
        f32x4 a0 = __builtin_amdgcn_mfma_f32_16x16x32_bf16(kf0, qf[0][0], z4, 0, 0, 0); \
        a0 = __builtin_amdgcn_mfma_f32_16x16x32_bf16(kf1, qf[0][1], a0, 0, 0, 0);       \
        f32x4 a1 = __builtin_amdgcn_mfma_f32_16x16x32_bf16(kf0, qf[1][0], z4, 0, 0, 0); \
        a1 = __builtin_amdgcn_mfma_f32_16x16x32_bf16(kf1, qf[1][1], a1, 0, 0, 0);       \
        {                                                                      \
          const float e0 = EXP2F(a0[0]);                                       \
          const float e1 = EXP2F(a0[1]);                                       \
          const float e2 = EXP2F(a0[2]);                                       \
          const float e3 = EXP2F(a0[3]);                                       \
          lsum[0] += (e0 + e1) + (e2 + e3);                                    \
          pfu0.u[2 * h2]     = PACK2BF(__float_as_uint(e1), __float_as_uint(e0)); \
          pfu0.u[2 * h2 + 1] = PACK2BF(__float_as_uint(e3), __float_as_uint(e2)); \
        }                                                                      \
        {                                                                      \
          const float e0 = EXP2F(a1[0]);                                       \
          const float e1 = EXP2F(a1[1]);                                       \
          const float e2 = EXP2F(a1[2]);                                       \
          const float e3 = EXP2F(a1[3]);                                       \
          lsum[1] += (e0 + e1) + (e2 + e3);                                    \
          pfu1.u[2 * h2]     = PACK2BF(__float_as_uint(e1), __float_as_uint(e0)); \
          pfu1.u[2 * h2 + 1] = PACK2BF(__float_as_uint(e3), __float_as_uint(e2)); \
        }                                                                      \
      }                                                                        \
      const short8 pf0 = pfu0.v, pf1 = pfu1.v;                                 \
      _Pragma("unroll")                                                        \
      for (int dt = 0; dt < 4; dt++) {                                         \
        const short8 vf = *(const short8*)&Vb_[(dt * 16 + l16) * 64 + (ks ? u1 : u0)]; \
        o[0][dt] = __builtin_amdgcn_mfma_f32_16x16x32_bf16(pf0, vf, o[0][dt], 0, 0, 0); \
        o[1][dt] = __builtin_amdgcn_mfma_f32_16x16x32_bf16(pf1, vf, o[1][dt], 0, 0, 0); \
      }                                                                        \
    }                                                                          \
  } while (0)

__global__ void __launch_bounds__(256, 3) attn_flash(const ushort* __restrict__ qk,
                                                     const ushort* __restrict__ vtg,
                                                     ushort* __restrict__ pob,
                                                     float* __restrict__ pl,
                                                     int ntiles, int nsl8) {
  __shared__ __align__(16) ushort Ks[3][64 * 64];   // 24 KB
  __shared__ __align__(16) ushort Vs[3][64 * 64];   // 24 KB

  const int b = blockIdx.x;
  const int s8 = b & 7;               // presumed XCD (round-robin dispatch)
  const int j = b >> 3;
  const int slice = s8 + 8 * (j % nsl8);   // 0..12*S-1, pinned to XCD s8
  const int qb = j / nsl8;                 // 0..31
  const int h = slice % NHEAD;
  const int sp = slice / NHEAD;            // 0..S-1

  const int tid = threadIdx.x;
  const int wave = tid >> 6, lane = tid & 63, quad = lane >> 4, l16 = lane & 15;
  const int q0 = qb * 128 + wave * 32;     // this wave's first q row

  // Q fragments (B-operand). Pre-scaled by log2e/8 in gemm_qkv.
  short8 qf[2][2];
#pragma unroll
  for (int s = 0; s < 2; s++) {
    const ushort* qp = qk + (size_t)(q0 + s * 16 + l16) * QK_LD + h * 64 + quad * 8;
    qf[s][0] = *(const short8*)qp;
    qf[s][1] = *(const short8*)(qp + 32);
  }

  // ---- staging source addresses (linear LDS dest; perm+swizzle on global src) ----
  const int srow = wave * 16 + (lane >> 3);                 // i=0 row (i=1: +8, same &7)
  const int un = (((lane & 7) ^ (lane >> 3)) * 8);          // swizzled unit, ushorts
  const int g0 = ((srow >> 5) << 5) + (((srow >> 2) & 3) << 3) +
                 (((srow >> 4) & 1) << 2) + (srow & 3);     // siginv(srow); +8 rows -> +16
  const int kt0 = sp * ntiles;
  const ushort* kp0 = qk + 768 + h * 64 + un + (size_t)(kt0 * 64 + g0) * QK_LD;
  const ushort* kp1 = kp0 + (size_t)16 * QK_LD;
  const ushort* vp0 = vtg + (size_t)(h * 64 + srow) * N_TOK + kt0 * 64 + un;
  const ushort* vp1 = vp0 + (size_t)8 * N_TOK;

  // read-side swizzled column offsets (row&7 == l16&7 for all 16-row strips)
  const int u0 = (quad ^ (l16 & 7)) * 8;
  const int u1 = u0 ^ 32;

  f32x4 o[2][4] = {};
  float lsum[2] = {};
  const f32x4 z4 = {};   // hoisted zero quad: QK-MFMA C operand, zeroed ONCE

  // prologue: DMA tiles 0,1 into buf0,buf1; wait tile0 only (tile1 in flight)
  ATTN_STAGE(0);
  ATTN_STAGE(1);
  WAITBAR4();

  int bc = 0;            // compute buffer for tile kt
  int bs = 2;            // stage target for tile kt+2
  for (int kt = 0; kt < ntiles; kt++) {
    const bool more = (kt + 2 < ntiles);
    if (more) ATTN_STAGE(bs);
    ATTN_TILE(Ks[bc], Vs[bc]);
    if (more) WAITBAR4(); else WAITBAR0();
    bc = (bc == 2) ? 0 : bc + 1;
    bs = (bs == 2) ? 0 : bs + 1;
  }

  // ---- epilogue: reduce lsum across quads, redistribute to o's row indexing ----
#pragma unroll
  for (int s = 0; s < 2; s++) {
    float lt = lsum[s];
    lt += __shfl_xor(lt, 16, 64);
    lt += __shfl_xor(lt, 32, 64);          // lt = l for q-row (s*16 + l16)
#pragma unroll
    for (int rr = 0; rr < 4; rr++) {
      const float l = __shfl(lt, quad * 16 + quad * 4 + rr, 64);
      const float inv = 1.f / l;
      const int row = q0 + s * 16 + quad * 4 + rr;
      if (l16 == 0)
        pl[(size_t)(sp * NHEAD + h) * N_TOK + row] = l;
#pragma unroll
      for (int dt = 0; dt < 4; dt++)
        pob[((size_t)sp * N_TOK + row) * DMODEL + h * 64 + dt * 16 + l16] =
            bf16bits(o[s][dt][rr] * inv);
    }
  }
}

// ---- combine S split partials: aout = sum(l_s * o_s) / sum(l_s), bf16 ----
__global__ void __launch_bounds__(256) combine(const ushort* __restrict__ pob,
                                               const float* __restrict__ pl,
                                               ushort* __restrict__ aout, int S) {
  const int i = blockIdx.x * 256 + threadIdx.x;   // ushort4 index
  const int row = i / (DMODEL / 4);
  const int hd = (i % (DMODEL / 4)) * 4;
  const int h = hd >> 6;
  float lt = 0.f, a0 = 0.f, a1 = 0.f, a2 = 0.f, a3 = 0.f;
  for (int s = 0; s < S; s++) {
    const float l = pl[((size_t)s * NHEAD + h) * N_TOK + row];
    const ushort4 a = *(const ushort4*)&pob[((size_t)s * N_TOK + row) * DMODEL + hd];
    lt += l;
    a0 += l * bf2f(a.x); a1 += l * bf2f(a.y); a2 += l * bf2f(a.z); a3 += l * bf2f(a.w);
  }
  const float inv = 1.f / lt;
  ushort4 r;
  r.x = bf16bits(a0 * inv); r.y = bf16bits(a1 * inv);
  r.z = bf16bits(a2 * inv); r.w = bf16bits(a3 * inv);
  *(ushort4*)&aout[(size_t)row * DMODEL + hd] = r;
}

extern "C" void kernel_launch(void* const* d_in, const int* in_sizes, int n_in,
                              void* d_out, int out_size, void* d_ws, size_t ws_size,
                              hipStream_t stream) {
  const float* x     = (const float*)d_in[0];
  const float* w_qkv = (const float*)d_in[1];
  const float* w_out = (const float*)d_in[2];
  const float* b_out = (const float*)d_in[3];
  float* out = (float*)d_out;

  // ws layout (runtime split count S): pob at 0 (S*6.29 MB; xb/wqkvb alias its
  // head, both dead before attn); then qkb, vtg, woutb, pl. aout aliases qkb.
  const size_t PO_UNIT = 6291456UL;   // 4096*768*2
  const int S = (ws_size >= 4 * PO_UNIT + 20840448UL) ? 4 : 2;
  char* ws = (char*)d_ws;
  ushort* pob   = (ushort*)ws;
  ushort* xb    = (ushort*)ws;                          // [0, 6.29M) dead after gemm1
  ushort* wqkvb = (ushort*)(ws + 6291456UL);            // [6.29M, 9.83M) dead after gemm1
  ushort* qkb   = (ushort*)(ws + (size_t)S * PO_UNIT);
  ushort* vtg   = (ushort*)((char*)qkb + 12582912UL);
  ushort* woutb = (ushort*)((char*)vtg + 6291456UL);
  float*  pl    = (float*)((char*)woutb + 1179648UL);
  ushort* aoutb = qkb;                                  // qkb dead after attn

  // 1) converts (one kernel, 3 ranges: 3072 + 1728 + 576 blocks)
  cvt3<<<5376, 256, 0, stream>>>(x, w_qkv, w_out, xb, wqkvb, woutb);

  // 2) qkv GEMM, 128x96 tiles: grid 24x32 = 768 blocks = exactly 3/CU
  gemm_qkv<<<dim3(24, 32), 256, 0, stream>>>(xb, wqkvb, qkb, vtg);

  // 3) flash attention (triple-buffer counted-vmcnt; 128 q-rows/block, KV-split-S)
  attn_flash<<<384 * S, 256, 0, stream>>>(qkb, vtg, pob, pl, 64 / S, (12 * S) / 8);

  // 4) combine partials -> aout bf16
  combine<<<3072, 256, 0, stream>>>(pob, pl, aoutb, S);

  // 5) out = aout @ w_out^T + b_out (fp32 out), 64x64 tiles, 768 blocks = 3/CU
  gemm_out<<<dim3(12, 64), 256, 0, stream>>>(aoutb, woutb, out, b_out);
}

// Round 16
// 185.382 us; speedup vs baseline: 1.0548x; 1.0095x over previous
//
#include <hip/hip_runtime.h>

// ClassicalSelfAttention: B=1, N=4096, D=768, H=12, Hd=64, fp32 in/out.
// R25 = R24 (verified 187.1us; attn triple-buffer counted-vmcnt = 62.3us) with
// the SAME verified pipeline structure applied to both GEMMs, which still ran
// the serial form {stage THIS tile -> sync -> compute -> sync} (DMA latency
// serial in every K-step -- the exact pattern attn had before R14):
//  - gemm_qkv: BM 128->64 so a DOUBLE buffer fits hot: LDS 40KB -> 4 blocks/CU,
//    grid (24,64)=1536. Wave tile 32x48, acc[2][3]. Loop: stage(next) fire-and-
//    forget -> compute(cur) -> one __syncthreads. Bit-identical accumulation.
//  - gemm_out: double-buffered in place (2x16KB=32KB, still 3/CU exact).
// attn/cvt3/combine byte-identical to R24.
// Falsifiers: absmax != 0.001953125 -> revert; total > 188 -> revert GEMMs.

typedef __attribute__((ext_vector_type(8))) short short8;   // 8 x bf16 fragment
typedef __attribute__((ext_vector_type(4))) float f32x4;    // MFMA accumulator

#define N_TOK 4096
#define NHEAD 12
#define DMODEL 768
#define QK_LD 1536

#if defined(__has_builtin)
#if __has_builtin(__builtin_amdgcn_exp2f)
#define EXP2F __builtin_amdgcn_exp2f
#else
#define EXP2F exp2f
#endif
#else
#define EXP2F exp2f
#endif

#if defined(__has_builtin)
#if __has_builtin(__builtin_amdgcn_perm)
#define PACK2BF(hi, lo) __builtin_amdgcn_perm((hi), (lo), 0x07060302u)
#else
#define PACK2BF(hi, lo) ((((hi)) & 0xffff0000u) | (((lo)) >> 16))
#endif
#else
#define PACK2BF(hi, lo) ((((hi)) & 0xffff0000u) | (((lo)) >> 16))
#endif

__device__ __forceinline__ ushort bf16bits(float x) {
  union { float f; unsigned u; } cv; cv.f = x;
  unsigned u = cv.u;
  u += 0x7fffu + ((u >> 16) & 1u);   // RNE
  return (ushort)(u >> 16);
}
__device__ __forceinline__ float bf2f(ushort u) {
  return __uint_as_float(((unsigned)u) << 16);
}

// async global->LDS, 16 B per lane; lds base must be wave-uniform, HW scatters lane*16.
__device__ __forceinline__ void async16(ushort* lds, const ushort* g) {
  __builtin_amdgcn_global_load_lds((const __attribute__((address_space(1))) unsigned int*)g,
                                   (__attribute__((address_space(3))) unsigned int*)lds,
                                   16, 0, 0);
}

// ---- fused fp32->bf16 converts for x (3072 blk), w_qkv (1728 blk), w_out (576 blk) ----
__global__ void __launch_bounds__(256) cvt3(const float* __restrict__ x,
                                            const float* __restrict__ wq,
                                            const float* __restrict__ wo,
                                            ushort* __restrict__ xb,
                                            ushort* __restrict__ wqb,
                                            ushort* __restrict__ wob) {
  const int b = blockIdx.x, t = threadIdx.x;
  const float* src; ushort* dst; int i;
  if (b < 3072)      { src = x;  dst = xb;  i = b * 256 + t; }           // 786432 f4
  else if (b < 4800) { src = wq; dst = wqb; i = (b - 3072) * 256 + t; }  // 442368 f4
  else               { src = wo; dst = wob; i = (b - 4800) * 256 + t; }  // 147456 f4
  const float4 v = ((const float4*)src)[i];
  ushort4 o;
  o.x = bf16bits(v.x); o.y = bf16bits(v.y); o.z = bf16bits(v.z); o.w = bf16bits(v.w);
  ((ushort4*)dst)[i] = o;
}

#define GEMM_STAGE96(Ms, Mp, MK)                                               \
  do {                                                                         \
    _Pragma("unroll")                                                          \
    for (int i_ = 0; i_ < 3; i_++)                                             \
      async16(&(Ms)[(wave * 24 + i_ * 8) * 64],                                \
              Mp + (size_t)(wave * 24 + i_ * 8 + lrow) * (MK) + lcol);         \
  } while (0)

#define GEMM_STAGE64(Ms, Mp, MK)                                               \
  do {                                                                         \
    _Pragma("unroll")                                                          \
    for (int i_ = 0; i_ < 2; i_++)                                             \
      async16(&(Ms)[(wave * 16 + i_ * 8) * 64],                                \
              Mp + (size_t)(wave * 16 + i_ * 8 + lrow) * (MK) + lcol);         \
  } while (0)

// ---- GEMM1: qkv = x @ w_qkv^T.  64x96 tiles, DOUBLE-BUFFERED (40KB, 4/CU).
//      Grid (24,64) = 1536. Loop: stage(next) -> compute(cur) -> syncthreads.
//      Q cols pre-scaled by log2e/8 -> qk[n][1536]; V cols -> vtg[h*64+d][n].
__global__ void __launch_bounds__(256) gemm_qkv(const ushort* __restrict__ A,
                                                const ushort* __restrict__ B,
                                                ushort* __restrict__ qkb,
                                                ushort* __restrict__ vtg) {
  __shared__ __align__(16) ushort As[2][64 * 64];   // 2 x 8 KB
  __shared__ __align__(16) ushort Bs[2][96 * 64];   // 2 x 12 KB
  const int tid = threadIdx.x;
  const int wave = tid >> 6, lane = tid & 63, quad = lane >> 4, l16 = lane & 15;
  const int wm = wave & 1, wn = wave >> 1;     // 2x2 waves: 32-row x 48-col tiles
  const int lrow = lane >> 3, lcol = (lane & 7) * 8;
  const int m0 = blockIdx.y * 64, n0 = blockIdx.x * 96;
  const int K = DMODEL;

  f32x4 acc[2][3] = {};
  const ushort* Ap = A + (size_t)m0 * K;
  const ushort* Bp = B + (size_t)n0 * K;

  // prologue: stage K-step 0 into buf 0
  GEMM_STAGE64(As[0], Ap, K);
  GEMM_STAGE96(Bs[0], Bp, K);
  __syncthreads();

  for (int k0 = 0; k0 < K; k0 += 64) {
    const int cur = (k0 >> 6) & 1, nxt = cur ^ 1;
    if (k0 + 64 < K) {                       // stage next tile, fire-and-forget
      GEMM_STAGE64(As[nxt], Ap + k0 + 64, K);
      GEMM_STAGE96(Bs[nxt], Bp + k0 + 64, K);
    }
#pragma unroll
    for (int ks = 0; ks < 2; ks++) {
      short8 af[2], bf[3];
#pragma unroll
      for (int i = 0; i < 2; i++)
        af[i] = *(const short8*)&As[cur][(wm * 32 + i * 16 + l16) * 64 + ks * 32 + quad * 8];
#pragma unroll
      for (int i = 0; i < 3; i++)
        bf[i] = *(const short8*)&Bs[cur][(wn * 48 + i * 16 + l16) * 64 + ks * 32 + quad * 8];
#pragma unroll
      for (int mi = 0; mi < 2; mi++)
#pragma unroll
        for (int ni = 0; ni < 3; ni++)
          acc[mi][ni] = __builtin_amdgcn_mfma_f32_16x16x32_bf16(af[mi], bf[ni], acc[mi][ni], 0, 0, 0);
    }
    __syncthreads();   // drains vmcnt (next stage landed) + lgkm (cur reads done)
  }

  if (n0 < QK_LD) {
    // Q/K epilogue (tiles never straddle 768: 768/96 = 8 blocks exactly).
    const float qsc = (n0 < 768) ? 0.18033688011112042f : 1.0f;  // log2(e)/8
#pragma unroll
    for (int mi = 0; mi < 2; mi++)
#pragma unroll
      for (int ni = 0; ni < 3; ni++) {
        const int col = n0 + wn * 48 + ni * 16 + l16;
#pragma unroll
        for (int rr = 0; rr < 4; rr++) {
          const int row = m0 + wm * 32 + mi * 16 + quad * 4 + rr;
          qkb[(size_t)row * QK_LD + col] = bf16bits(acc[mi][ni][rr] * qsc);
        }
      }
  } else {
    // V epilogue: vtg[col-1536][row], 4 consecutive rows packed per lane.
#pragma unroll
    for (int mi = 0; mi < 2; mi++)
#pragma unroll
      for (int ni = 0; ni < 3; ni++) {
        const int col = n0 + wn * 48 + ni * 16 + l16 - QK_LD;   // = h*64+d
        const int rowb = m0 + wm * 32 + mi * 16 + quad * 4;
        const unsigned u0 = (unsigned)bf16bits(acc[mi][ni][0]) |
                            ((unsigned)bf16bits(acc[mi][ni][1]) << 16);
        const unsigned u1 = (unsigned)bf16bits(acc[mi][ni][2]) |
                            ((unsigned)bf16bits(acc[mi][ni][3]) << 16);
        *(uint2*)&vtg[(size_t)col * N_TOK + rowb] = make_uint2(u0, u1);
      }
  }
}

// ---- GEMM2: out = aout @ w_out^T + bias (fp32 out), 64x64 tiles, DOUBLE-BUF ----
// LDS 32KB (still 3/CU exact at grid (12,64)). stage(next) -> compute -> sync.
__global__ void __launch_bounds__(256) gemm_out(const ushort* __restrict__ A,
                                                const ushort* __restrict__ B,
                                                float* __restrict__ Cf,
                                                const float* __restrict__ bias) {
  __shared__ __align__(16) ushort As[2][64 * 64];
  __shared__ __align__(16) ushort Bs[2][64 * 64];
  const int tid = threadIdx.x;
  const int wave = tid >> 6, lane = tid & 63, quad = lane >> 4, l16 = lane & 15;
  const int wm = wave & 1, wn = wave >> 1;
  const int lrow = lane >> 3, lcol = (lane & 7) * 8;
  const int m0 = blockIdx.y * 64, n0 = blockIdx.x * 64;
  const int K = DMODEL, Nn = DMODEL;

  f32x4 acc[2][2] = {};
  const ushort* Ap = A + (size_t)m0 * K;
  const ushort* Bp = B + (size_t)n0 * K;

  GEMM_STAGE64(As[0], Ap, K);
  GEMM_STAGE64(Bs[0], Bp, K);
  __syncthreads();

  for (int k0 = 0; k0 < K; k0 += 64) {
    const int cur = (k0 >> 6) & 1, nxt = cur ^ 1;
    if (k0 + 64 < K) {
      GEMM_STAGE64(As[nxt], Ap + k0 + 64, K);
      GEMM_STAGE64(Bs[nxt], Bp + k0 + 64, K);
    }
#pragma unroll
    for (int ks = 0; ks < 2; ks++) {
      short8 af[2], bf[2];
#pragma unroll
      for (int i = 0; i < 2; i++) {
        af[i] = *(const short8*)&As[cur][(wm * 32 + i * 16 + l16) * 64 + ks * 32 + quad * 8];
        bf[i] = *(const short8*)&Bs[cur][(wn * 32 + i * 16 + l16) * 64 + ks * 32 + quad * 8];
      }
#pragma unroll
      for (int mi = 0; mi < 2; mi++)
#pragma unroll
        for (int ni = 0; ni < 2; ni++)
          acc[mi][ni] = __builtin_amdgcn_mfma_f32_16x16x32_bf16(af[mi], bf[ni], acc[mi][ni], 0, 0, 0);
    }
    __syncthreads();
  }

#pragma unroll
  for (int mi = 0; mi < 2; mi++)
#pragma unroll
    for (int ni = 0; ni < 2; ni++) {
      const int col = n0 + wn * 32 + ni * 16 + l16;
#pragma unroll
      for (int rr = 0; rr < 4; rr++) {
        const int row = m0 + wm * 32 + mi * 16 + quad * 4 + rr;
        Cf[(size_t)row * Nn + col] = acc[mi][ni][rr] + bias[col];
      }
    }
}

// ---- Flash attention: 128 q-rows/block (32/wave), triple-buffered DMA LDS ----
// (R24, verified 62.3us.) Counted-vmcnt barriers: stage(kt+2) stays in flight
// across the barrier; only stage(kt+1) (issued a full iteration ago) must land.

#define ATTN_STAGE(bufi)                                                       \
  do {                                                                         \
    async16(&Ks[bufi][(wave * 16) * 64],     kp0);                             \
    async16(&Ks[bufi][(wave * 16 + 8) * 64], kp1);                             \
    async16(&Vs[bufi][(wave * 16) * 64],     vp0);                             \
    async16(&Vs[bufi][(wave * 16 + 8) * 64], vp1);                             \
    kp0 += (size_t)64 * QK_LD; kp1 += (size_t)64 * QK_LD;                      \
    vp0 += 64; vp1 += 64;                                                      \
  } while (0)

#define WAITBAR4()                                                             \
  do {                                                                         \
    asm volatile("s_waitcnt vmcnt(4) lgkmcnt(0)" ::: "memory");                \
    __builtin_amdgcn_s_barrier();                                              \
  } while (0)

#define WAITBAR0()                                                             \
  do {                                                                         \
    asm volatile("s_waitcnt vmcnt(0) lgkmcnt(0)" ::: "memory");                \
    __builtin_amdgcn_s_barrier();                                              \
  } while (0)

#define ATTN_TILE(KbP, VbP)                                                    \
  do {                                                                         \
    const ushort* Kb_ = (KbP);                                                 \
    const ushort* Vb_ = (VbP);                                                 \
    _Pragma("unroll")                                                          \
    for (int ks = 0; ks < 2; ks++) {                                           \
      union { unsigned u[4]; short8 v; } pfu0, pfu1;                           \
      _Pragma("unroll")                                                        \
      for (int h2 = 0; h2 < 2; h2++) {                                         \
        const int nt = 2 * ks + h2;                                            \
        const short8 kf0 = *(const short8*)&Kb_[(nt * 16 + l16) * 64 + u0];    \
        const short8 kf1 = *(const short8*)&Kb_[(nt * 16 + l16) * 64 + u1];    \
        f32x4 a0 = __builtin_amdgcn_mfma_f32_16x16x32_bf16(kf0, qf[0][0], z4, 0, 0, 0); \
        a0 = __builtin_amdgcn_mfma_f32_16x16x32_bf16(kf1, qf[0][1], a0, 0, 0, 0);       \
        f32x4 a1 = __builtin_amdgcn_mfma_f32_16x16x32_bf16(kf0, qf[1][0], z4, 0, 0, 0); \
        a1 = __builtin_amdgcn_mfma_f32_16x16x32_bf16(kf1, qf[1][1], a1, 0, 0, 0);       \
        {                                                                      \
          const float e0 = EXP2F(a0[0]);                                       \
          const float e1 = EXP2F(a0[1]);                                       \
          const float e2 = EXP2F(a0[2]);                                       \
          const float e3 = EXP2F(a0[3]);                                       \
          lsum[0] += (e0 + e1) + (e2 + e3);                                    \
          pfu0.u[2 * h2]     = PACK2BF(__float_as_uint(e1), __float_as_uint(e0)); \
          pfu0.u[2 * h2 + 1] = PACK2BF(__float_as_uint(e3), __float_as_uint(e2)); \
        }                                                                      \
        {                                                                      \
          const float e0 = EXP2F(a1[0]);                                       \
          const float e1 = EXP2F(a1[1]);                                       \
          const float e2 = EXP2F(a1[2]);                                       \
          const float e3 = EXP2F(a1[3]);                                       \
          lsum[1] += (e0 + e1) + (e2 + e3);                                    \
          pfu1.u[2 * h2]     = PACK2BF(__float_as_uint(e1), __float_as_uint(e0)); \
          pfu1.u[2 * h2 + 1] = PACK2BF(__float_as_uint(e3), __float_as_uint(e2)); \
        }                                                                      \
      }                                                                        \
      const short8 pf0 = pfu0.v, pf1 = pfu1.v;                                 \
      _Pragma("unroll")                                                        \
      for (int dt = 0; dt < 4; dt++) {                                         \
        const short8 vf = *(const short8*)&Vb_[(dt * 16 + l16) * 64 + (ks ? u1 : u0)]; \
        o[0][dt] = __builtin_amdgcn_mfma_f32_16x16x32_bf16(pf0, vf, o[0][dt], 0, 0, 0); \
        o[1][dt] = __builtin_amdgcn_mfma_f32_16x16x32_bf16(pf1, vf, o[1][dt], 0, 0, 0); \
      }                                                                        \
    }                                                                          \
  } while (0)

__global__ void __launch_bounds__(256, 3) attn_flash(const ushort* __restrict__ qk,
                                                     const ushort* __restrict__ vtg,
                                                     ushort* __restrict__ pob,
                                                     float* __restrict__ pl,
                                                     int ntiles, int nsl8) {
  __shared__ __align__(16) ushort Ks[3][64 * 64];   // 24 KB
  __shared__ __align__(16) ushort Vs[3][64 * 64];   // 24 KB

  const int b = blockIdx.x;
  const int s8 = b & 7;               // presumed XCD (round-robin dispatch)
  const int j = b >> 3;
  const int slice = s8 + 8 * (j % nsl8);   // 0..12*S-1, pinned to XCD s8
  const int qb = j / nsl8;                 // 0..31
  const int h = slice % NHEAD;
  const int sp = slice / NHEAD;            // 0..S-1

  const int tid = threadIdx.x;
  const int wave = tid >> 6, lane = tid & 63, quad = lane >> 4, l16 = lane & 15;
  const int q0 = qb * 128 + wave * 32;     // this wave's first q row

  // Q fragments (B-operand). Pre-scaled by log2e/8 in gemm_qkv.
  short8 qf[2][2];
#pragma unroll
  for (int s = 0; s < 2; s++) {
    const ushort* qp = qk + (size_t)(q0 + s * 16 + l16) * QK_LD + h * 64 + quad * 8;
    qf[s][0] = *(const short8*)qp;
    qf[s][1] = *(const short8*)(qp + 32);
  }

  // ---- staging source addresses (linear LDS dest; perm+swizzle on global src) ----
  const int srow = wave * 16 + (lane >> 3);                 // i=0 row (i=1: +8, same &7)
  const int un = (((lane & 7) ^ (lane >> 3)) * 8);          // swizzled unit, ushorts
  const int g0 = ((srow >> 5) << 5) + (((srow >> 2) & 3) << 3) +
                 (((srow >> 4) & 1) << 2) + (srow & 3);     // siginv(srow); +8 rows -> +16
  const int kt0 = sp * ntiles;
  const ushort* kp0 = qk + 768 + h * 64 + un + (size_t)(kt0 * 64 + g0) * QK_LD;
  const ushort* kp1 = kp0 + (size_t)16 * QK_LD;
  const ushort* vp0 = vtg + (size_t)(h * 64 + srow) * N_TOK + kt0 * 64 + un;
  const ushort* vp1 = vp0 + (size_t)8 * N_TOK;

  // read-side swizzled column offsets (row&7 == l16&7 for all 16-row strips)
  const int u0 = (quad ^ (l16 & 7)) * 8;
  const int u1 = u0 ^ 32;

  f32x4 o[2][4] = {};
  float lsum[2] = {};
  const f32x4 z4 = {};   // hoisted zero quad: QK-MFMA C operand, zeroed ONCE

  // prologue: DMA tiles 0,1 into buf0,buf1; wait tile0 only (tile1 in flight)
  ATTN_STAGE(0);
  ATTN_STAGE(1);
  WAITBAR4();

  int bc = 0;            // compute buffer for tile kt
  int bs = 2;            // stage target for tile kt+2
  for (int kt = 0; kt < ntiles; kt++) {
    const bool more = (kt + 2 < ntiles);
    if (more) ATTN_STAGE(bs);
    ATTN_TILE(Ks[bc], Vs[bc]);
    if (more) WAITBAR4(); else WAITBAR0();
    bc = (bc == 2) ? 0 : bc + 1;
    bs = (bs == 2) ? 0 : bs + 1;
  }

  // ---- epilogue: reduce lsum across quads, redistribute to o's row indexing ----
#pragma unroll
  for (int s = 0; s < 2; s++) {
    float lt = lsum[s];
    lt += __shfl_xor(lt, 16, 64);
    lt += __shfl_xor(lt, 32, 64);          // lt = l for q-row (s*16 + l16)
#pragma unroll
    for (int rr = 0; rr < 4; rr++) {
      const float l = __shfl(lt, quad * 16 + quad * 4 + rr, 64);
      const float inv = 1.f / l;
      const int row = q0 + s * 16 + quad * 4 + rr;
      if (l16 == 0)
        pl[(size_t)(sp * NHEAD + h) * N_TOK + row] = l;
#pragma unroll
      for (int dt = 0; dt < 4; dt++)
        pob[((size_t)sp * N_TOK + row) * DMODEL + h * 64 + dt * 16 + l16] =
            bf16bits(o[s][dt][rr] * inv);
    }
  }
}

// ---- combine S split partials: aout = sum(l_s * o_s) / sum(l_s), bf16 ----
__global__ void __launch_bounds__(256) combine(const ushort* __restrict__ pob,
                                               const float* __restrict__ pl,
                                               ushort* __restrict__ aout, int S) {
  const int i = blockIdx.x * 256 + threadIdx.x;   // ushort4 index
  const int row = i / (DMODEL / 4);
  const int hd = (i % (DMODEL / 4)) * 4;
  const int h = hd >> 6;
  float lt = 0.f, a0 = 0.f, a1 = 0.f, a2 = 0.f, a3 = 0.f;
  for (int s = 0; s < S; s++) {
    const float l = pl[((size_t)s * NHEAD + h) * N_TOK + row];
    const ushort4 a = *(const ushort4*)&pob[((size_t)s * N_TOK + row) * DMODEL + hd];
    lt += l;
    a0 += l * bf2f(a.x); a1 += l * bf2f(a.y); a2 += l * bf2f(a.z); a3 += l * bf2f(a.w);
  }
  const float inv = 1.f / lt;
  ushort4 r;
  r.x = bf16bits(a0 * inv); r.y = bf16bits(a1 * inv);
  r.z = bf16bits(a2 * inv); r.w = bf16bits(a3 * inv);
  *(ushort4*)&aout[(size_t)row * DMODEL + hd] = r;
}

extern "C" void kernel_launch(void* const* d_in, const int* in_sizes, int n_in,
                              void* d_out, int out_size, void* d_ws, size_t ws_size,
                              hipStream_t stream) {
  const float* x     = (const float*)d_in[0];
  const float* w_qkv = (const float*)d_in[1];
  const float* w_out = (const float*)d_in[2];
  const float* b_out = (const float*)d_in[3];
  float* out = (float*)d_out;

  // ws layout (runtime split count S): pob at 0 (S*6.29 MB; xb/wqkvb alias its
  // head, both dead before attn); then qkb, vtg, woutb, pl. aout aliases qkb.
  const size_t PO_UNIT = 6291456UL;   // 4096*768*2
  const int S = (ws_size >= 4 * PO_UNIT + 20840448UL) ? 4 : 2;
  char* ws = (char*)d_ws;
  ushort* pob   = (ushort*)ws;
  ushort* xb    = (ushort*)ws;                          // [0, 6.29M) dead after gemm1
  ushort* wqkvb = (ushort*)(ws + 6291456UL);            // [6.29M, 9.83M) dead after gemm1
  ushort* qkb   = (ushort*)(ws + (size_t)S * PO_UNIT);
  ushort* vtg   = (ushort*)((char*)qkb + 12582912UL);
  ushort* woutb = (ushort*)((char*)vtg + 6291456UL);
  float*  pl    = (float*)((char*)woutb + 1179648UL);
  ushort* aoutb = qkb;                                  // qkb dead after attn

  // 1) converts (one kernel, 3 ranges: 3072 + 1728 + 576 blocks)
  cvt3<<<5376, 256, 0, stream>>>(x, w_qkv, w_out, xb, wqkvb, woutb);

  // 2) qkv GEMM, 64x96 tiles double-buffered: grid (24,64) = 1536, 4/CU
  gemm_qkv<<<dim3(24, 64), 256, 0, stream>>>(xb, wqkvb, qkb, vtg);

  // 3) flash attention (triple-buffer counted-vmcnt; 128 q-rows/block, KV-split-S)
  attn_flash<<<384 * S, 256, 0, stream>>>(qkb, vtg, pob, pl, 64 / S, (12 * S) / 8);

  // 4) combine partials -> aout bf16
  combine<<<3072, 256, 0, stream>>>(pob, pl, aoutb, S);

  // 5) out = aout @ w_out^T + b_out (fp32 out), 64x64 double-buffered, 768 = 3/CU
  gemm_out<<<dim3(12, 64), 256, 0, stream>>>(aoutb, woutb, out, b_out);
}